// Round 12
// baseline (6976.155 us; speedup 1.0000x reference)
//
#include <hip/hip_runtime.h>
#include <stdint.h>

// Problem constants
#define TT 256      // timesteps per phase
#define BB 256      // batch
#define II 128      // input dim
#define SS 256      // state dim
#define NSTEP (2*TT)
#define NTEAM 16    // 16 blocks, one per 16 batch rows; NO inter-block comms

typedef _Float16 h16;
typedef _Float16 half8 __attribute__((ext_vector_type(8)));
typedef float f32x4 __attribute__((ext_vector_type(4)));

#define SBP 264     // s_lds row stride in halves (256 + 8 pad)

__device__ __forceinline__ float sigmoidf_(float z) {
    return __builtin_amdgcn_rcpf(1.0f + __expf(-z));
}
__device__ __forceinline__ float tanhf_(float z) {
    return 1.0f - 2.0f * __builtin_amdgcn_rcpf(1.0f + __expf(2.0f * z));
}

struct Ptrs {
    const float *x;
    const float *Wi, *Ui, *Bi, *Wf, *Uf, *Bf, *Wo, *Uo, *Bo, *Wg, *Ug, *Bg;
    float* out;
    uint32_t* ws;
};

// One block = one team of 16 batch rows, FULL state width S=256.
// 16 waves; wave w owns state cols [w*16, w*16+16) for ALL 4 gates:
//   registers: bU[4][8] (128 VGPR) + bW[4][4] (64) + acc[4] (16) + xv (32)
//   ~270 VGPR -> 4 waves/SIMD fits (4x270 < 2048), no spills.
// State exchange is pure LDS (double-buffered), ONE barrier per step.
// No cooperative launch, no workspace, no spin: nothing can hang.
__global__ __launch_bounds__(1024, 1) void lstm_team(Ptrs p) {
    const int tid  = threadIdx.x;
    const int w    = tid >> 6;             // wave 0..15
    const int lane = tid & 63;
    const int team = blockIdx.x;           // 0..15
    const int r0   = team * 16;            // batch rows [r0, r0+16)
    const int c0   = w * 16;               // state cols [c0, c0+16)
    const int lrow = lane & 15;            // A-row / C-col for this lane
    const int lgrp = lane >> 4;            // 0..3
    const int lk8  = lgrp * 8;             // k sub-offset within 32-chunk

    // double-buffered state: s_lds[parity][row][col]
    __shared__ __align__(16) h16 s_lds[2][16][SBP];

    const float* Uptr[4] = {p.Ui, p.Uf, p.Uo, p.Ug};
    const float* Wptr[4] = {p.Wi, p.Wf, p.Wo, p.Wg};
    const float* Bptr[4] = {p.Bi, p.Bf, p.Bo, p.Bg};

    // ---- preload ALL 4 gates' B-fragments for this wave's 16 cols ----
    // B (16x16x32): lane holds B[k=(lane>>4)*8+q][col=lane&15]  (r9/r11-proven)
    half8 bU[4][8];
#pragma unroll
    for (int g = 0; g < 4; ++g) {
        const float* Ug = Uptr[g];
#pragma unroll
        for (int kc = 0; kc < 8; ++kc)
#pragma unroll
            for (int q = 0; q < 8; ++q)
                bU[g][kc][q] = (h16)Ug[(size_t)(kc * 32 + lk8 + q) * SS + c0 + lrow];
    }
    half8 bW[4][4];
#pragma unroll
    for (int g = 0; g < 4; ++g) {
        const float* Wg = Wptr[g];
#pragma unroll
        for (int kc = 0; kc < 4; ++kc)
#pragma unroll
            for (int q = 0; q < 8; ++q)
                bW[g][kc][q] = (h16)Wg[(size_t)(kc * 32 + lk8 + q) * SS + c0 + lrow];
    }
    float bias[4];
#pragma unroll
    for (int g = 0; g < 4; ++g) bias[g] = Bptr[g][c0 + lrow];

    // cell state: lane owns cells (row = lgrp*4+q, col = c0+lrow), q=0..3
    float cst[4] = {0.f, 0.f, 0.f, 0.f};

    // s_0 = 0: zero parity-0 buffer (parity-1 is written before first read)
    for (int i = tid; i < 16 * SBP; i += 1024)
        ((h16*)s_lds[0])[i] = (h16)0.0f;

    // x A-fragments for step 1 (x_0): lane's row slice, 32 k-values
    float4 xv[8];
    {
        const float* xp = p.x + ((size_t)0 * BB + r0 + lrow) * II;
#pragma unroll
        for (int kc = 0; kc < 4; ++kc) {
            xv[2*kc]   = ((const float4*)(xp + kc * 32 + lk8))[0];
            xv[2*kc+1] = ((const float4*)(xp + kc * 32 + lk8))[1];
        }
    }
    __syncthreads();

    for (int n = 1; n <= NSTEP; ++n) {
        const bool enc = (n <= TT);
        const h16* sprev = &s_lds[(n - 1) & 1][0][0];

        // ---- s @ U: 32 MFMAs, 4 independent gate chains ----
        f32x4 acc[4];
#pragma unroll
        for (int g = 0; g < 4; ++g) acc[g] = (f32x4){0.f, 0.f, 0.f, 0.f};
#pragma unroll
        for (int kc = 0; kc < 8; ++kc) {
            half8 a = *(const half8*)&sprev[lrow * SBP + kc * 32 + lk8];
#pragma unroll
            for (int g = 0; g < 4; ++g)
                acc[g] = __builtin_amdgcn_mfma_f32_16x16x32_f16(a, bU[g][kc], acc[g], 0, 0, 0);
        }

        // ---- x @ W (encode only; xv prefetched during previous step) ----
        if (enc) {
#pragma unroll
            for (int kc = 0; kc < 4; ++kc) {
                half8 xa;
                xa[0] = (h16)xv[2*kc].x;   xa[1] = (h16)xv[2*kc].y;
                xa[2] = (h16)xv[2*kc].z;   xa[3] = (h16)xv[2*kc].w;
                xa[4] = (h16)xv[2*kc+1].x; xa[5] = (h16)xv[2*kc+1].y;
                xa[6] = (h16)xv[2*kc+1].z; xa[7] = (h16)xv[2*kc+1].w;
#pragma unroll
                for (int g = 0; g < 4; ++g)
                    acc[g] = __builtin_amdgcn_mfma_f32_16x16x32_f16(xa, bW[g][kc], acc[g], 0, 0, 0);
            }
        }

        // ---- gates + state update, in-register on C/D fragments ----
        // C/D: col = c0 + (lane&15), row = (lane>>4)*4 + q  (m89-verified)
        float sv[4], ov[4];
#pragma unroll
        for (int q = 0; q < 4; ++q) {
            float zi = acc[0][q] + bias[0];
            float zf = acc[1][q] + bias[1];
            float zo = acc[2][q] + bias[2];
            float zg = acc[3][q] + bias[3];
            float ig = sigmoidf_(zi), fg = sigmoidf_(zf);
            float og = sigmoidf_(zo), gg = tanhf_(zg);
            cst[q] = cst[q] * fg + gg * ig;
            sv[q] = tanhf_(cst[q]) * og;
            ov[q] = og;
        }

        // ---- publish s_n to the other LDS buffer ----
        {
            h16* scur = &s_lds[n & 1][0][0];
#pragma unroll
            for (int q = 0; q < 4; ++q)
                scur[(lgrp * 4 + q) * SBP + c0 + lrow] = (h16)sv[q];
        }

        // ---- off-critical-path: output store + next x prefetch ----
        if (!enc) {
            const int d = n - TT - 1;
#pragma unroll
            for (int q = 0; q < 4; ++q)
                p.out[((size_t)d * BB + r0 + lgrp * 4 + q) * SS + c0 + lrow] = ov[q];
        }
        if (n < TT) {
            const float* xp = p.x + ((size_t)n * BB + r0 + lrow) * II;
#pragma unroll
            for (int kc = 0; kc < 4; ++kc) {
                xv[2*kc]   = ((const float4*)(xp + kc * 32 + lk8))[0];
                xv[2*kc+1] = ((const float4*)(xp + kc * 32 + lk8))[1];
            }
        }

        __syncthreads();   // s_n visible to all waves; WAR safe via dbuf
    }
}

extern "C" void kernel_launch(void* const* d_in, const int* in_sizes, int n_in,
                              void* d_out, int out_size, void* d_ws, size_t ws_size,
                              hipStream_t stream) {
    Ptrs p;
    p.x  = (const float*)d_in[0];
    p.Wi = (const float*)d_in[1];  p.Ui = (const float*)d_in[2];  p.Bi = (const float*)d_in[3];
    p.Wf = (const float*)d_in[4];  p.Uf = (const float*)d_in[5];  p.Bf = (const float*)d_in[6];
    p.Wo = (const float*)d_in[7];  p.Uo = (const float*)d_in[8];  p.Bo = (const float*)d_in[9];
    p.Wg = (const float*)d_in[10]; p.Ug = (const float*)d_in[11]; p.Bg = (const float*)d_in[12];
    p.out = (float*)d_out;
    p.ws  = (uint32_t*)d_ws;

    // 16 fully independent blocks; plain launch; no workspace, no protocol.
    hipLaunchKernelGGL(lstm_team, dim3(NTEAM), dim3(1024), 0, stream, p);
}

// Round 13
// 2003.159 us; speedup vs baseline: 3.4826x; 3.4826x over previous
//
#include <hip/hip_runtime.h>
#include <stdint.h>

// Problem constants
#define TT 256      // timesteps per phase
#define BB 256      // batch
#define II 128      // input dim
#define SS 256      // state dim
#define NSTEP (2*TT)
#define NBLK 128    // 8 team-pairs x 16 col-blocks; each block runs chains A,B

typedef _Float16 h16;
typedef _Float16 half8 __attribute__((ext_vector_type(8)));
typedef float f32x4 __attribute__((ext_vector_type(4)));

#define SBP 264     // s_buf padded row stride (halves)
#define XBP 136     // xbuf padded row stride (halves)

// Exchange: [parity][team][row 0..15][col_pair 0..127] of u64
//   u64 = { hi: step tag, lo: 2 x fp16 (even col in low half) }
// Tag-in-data (r7/r9-proven): no flags, no drains. Aligned 8B accesses are
// single-copy atomic. Lap safety per chain: producer writes s_{n+2} into a
// slot only after gathering all of s_{n+1}, which requires every team block
// to have finished reading s_n from that slot.
#define XROW 128
#define XTEAM (16 * XROW)        // 2048 u64 per team
#define XPAR  (16 * XTEAM)       // 32768 u64 per parity

__device__ __forceinline__ float sigmoidf_(float z) {
    return __builtin_amdgcn_rcpf(1.0f + __expf(-z));
}
__device__ __forceinline__ float tanhf_(float z) {
    return 1.0f - 2.0f * __builtin_amdgcn_rcpf(1.0f + __expf(2.0f * z));
}

__device__ __forceinline__ uint64_t ld_ag64(const uint64_t* p) {
    return __hip_atomic_load(p, __ATOMIC_RELAXED, __HIP_MEMORY_SCOPE_AGENT);
}
__device__ __forceinline__ void st_ag64(uint64_t* p, uint64_t v) {
    __hip_atomic_store(p, v, __ATOMIC_RELAXED, __HIP_MEMORY_SCOPE_AGENT);
}

// 8 independent 8B device-coherent loads.
#define LD8_OPS                                                             \
        "global_load_dwordx2 %0, %8, off sc1\n\t"                           \
        "global_load_dwordx2 %1, %8, off offset:8 sc1\n\t"                  \
        "global_load_dwordx2 %2, %8, off offset:16 sc1\n\t"                 \
        "global_load_dwordx2 %3, %8, off offset:24 sc1\n\t"                 \
        "global_load_dwordx2 %4, %8, off offset:32 sc1\n\t"                 \
        "global_load_dwordx2 %5, %8, off offset:40 sc1\n\t"                 \
        "global_load_dwordx2 %6, %8, off offset:48 sc1\n\t"                 \
        "global_load_dwordx2 %7, %8, off offset:56 sc1"
#define LD8_OUTS(v)                                                         \
        : "=&v"(v[0]), "=&v"(v[1]), "=&v"(v[2]), "=&v"(v[3]),               \
          "=&v"(v[4]), "=&v"(v[5]), "=&v"(v[6]), "=&v"(v[7])

// issue-only: loads go in flight, no wait
__device__ __forceinline__ void ld8_issue(const uint64_t* p, uint64_t* v) {
    asm volatile(LD8_OPS LD8_OUTS(v) : "v"(p) : "memory");
}
// combined issue + wait (retry path; r9-proven)
__device__ __forceinline__ void ld8_wait(const uint64_t* p, uint64_t* v) {
    asm volatile(LD8_OPS "\n\ts_waitcnt vmcnt(0)" LD8_OUTS(v) : "v"(p) : "memory");
}
// waits with the gather registers TIED ("+v") so no consumer of v can be
// hoisted above the waitcnt (rule-18 hazard).
#define WAIT_TIE8_VM8(v)                                                    \
    asm volatile("s_waitcnt vmcnt(8)"                                       \
        : "+v"(v[0]), "+v"(v[1]), "+v"(v[2]), "+v"(v[3]),                   \
          "+v"(v[4]), "+v"(v[5]), "+v"(v[6]), "+v"(v[7]) :: "memory");      \
    __builtin_amdgcn_sched_barrier(0)
#define WAIT_TIE8_VM0(v)                                                    \
    asm volatile("s_waitcnt vmcnt(0)"                                       \
        : "+v"(v[0]), "+v"(v[1]), "+v"(v[2]), "+v"(v[3]),                   \
          "+v"(v[4]), "+v"(v[5]), "+v"(v[6]), "+v"(v[7]) :: "memory");      \
    __builtin_amdgcn_sched_barrier(0)

__device__ __forceinline__ void retry8(const uint64_t* gp, uint64_t* gv,
                                       uint32_t want) {
    for (;;) {
        bool ok = true;
#pragma unroll
        for (int j = 0; j < 8; ++j)
            ok = ok && ((uint32_t)(gv[j] >> 32) == want);
        if (__builtin_expect(ok, 1)) break;
        ld8_wait(gp, gv);
    }
}

struct Ptrs {
    const float *x;
    const float *Wi, *Ui, *Bi, *Wf, *Uf, *Bf, *Wo, *Uo, *Bo, *Wg, *Ug, *Bg;
    float* out;
    uint32_t* ws;
};

__global__ __launch_bounds__(256, 1) void lstm2(Ptrs p) {
    const int bid  = blockIdx.x;
    const int tid  = threadIdx.x;
    const int wave = tid >> 6;            // gate: 0=i 1=f 2=o 3=g
    const int lane = tid & 63;
    const int lrow = lane & 15;           // A-row / B-col within tile
    const int lk8  = (lane >> 4) * 8;     // k sub-offset within 32-chunk
    const int erow = tid >> 4;            // elementwise (row,col) ownership
    const int ecol = tid & 15;

    const int tp = bid >> 4;              // team pair 0..7
    const int c  = bid & 15;              // col block 0..15
    const int teamA = tp, teamB = tp + 8;
    const int r0A = teamA * 16, r0B = teamB * 16;
    const int c0  = c * 16;

    __shared__ __align__(16) h16 sA[16 * SBP];
    __shared__ __align__(16) h16 sB[16 * SBP];
    __shared__ __align__(16) h16 xbA[16 * XBP];
    __shared__ __align__(16) h16 xbB[16 * XBP];
    __shared__ float zbA[4][16][17];
    __shared__ float zbB[4][16][17];
    __shared__ float biasLds[4][16];

    uint64_t* xch = (uint64_t*)p.ws;
    uint64_t* slotA[2] = { xch + (size_t)teamA * XTEAM,
                           xch + XPAR + (size_t)teamA * XTEAM };
    uint64_t* slotB[2] = { xch + (size_t)teamB * XTEAM,
                           xch + XPAR + (size_t)teamB * XTEAM };

    const float* Uptr[4] = {p.Ui, p.Uf, p.Uo, p.Ug};
    const float* Wptr[4] = {p.Wi, p.Wf, p.Wo, p.Wg};
    const float* Bptr[4] = {p.Bi, p.Bf, p.Bo, p.Bg};

    if (tid < 64) biasLds[tid >> 4][tid & 15] = Bptr[tid >> 4][c0 + (tid & 15)];
    for (int idx = tid; idx < 16 * SBP; idx += 256) {
        sA[idx] = (h16)0.0f;
        sB[idx] = (h16)0.0f;
    }

    // Weight fragments: SAME columns for chains A and B -> one copy.
    // B (16x16x32): lane holds B[k=(lane>>4)*8+q][col=lane&15]  (r9-proven)
    const float* Ug = Uptr[wave];
    const float* Wg = Wptr[wave];
    half8 bU[8];
#pragma unroll
    for (int kc = 0; kc < 8; ++kc)
#pragma unroll
        for (int q = 0; q < 8; ++q)
            bU[kc][q] = (h16)Ug[(size_t)(kc * 32 + lk8 + q) * SS + c0 + lrow];
    half8 bW[4];
#pragma unroll
    for (int kc = 0; kc < 4; ++kc)
#pragma unroll
        for (int q = 0; q < 8; ++q)
            bW[kc][q] = (h16)Wg[(size_t)(kc * 32 + lk8 + q) * SS + c0 + lrow];

    float cstA = 0.0f, cstB = 0.0f;

    // stage x_0 for both chains; prefetch x_1 regs
    float4 paA, pbA, paB, pbB;
    {
        const float* xa = p.x + ((size_t)0 * BB + r0A + erow) * II + ecol * 8;
        const float* xb = p.x + ((size_t)0 * BB + r0B + erow) * II + ecol * 8;
        float4 a0 = ((const float4*)xa)[0], a1 = ((const float4*)xa)[1];
        float4 b0 = ((const float4*)xb)[0], b1 = ((const float4*)xb)[1];
        half8 ha, hb;
        ha[0]=(h16)a0.x; ha[1]=(h16)a0.y; ha[2]=(h16)a0.z; ha[3]=(h16)a0.w;
        ha[4]=(h16)a1.x; ha[5]=(h16)a1.y; ha[6]=(h16)a1.z; ha[7]=(h16)a1.w;
        hb[0]=(h16)b0.x; hb[1]=(h16)b0.y; hb[2]=(h16)b0.z; hb[3]=(h16)b0.w;
        hb[4]=(h16)b1.x; hb[5]=(h16)b1.y; hb[6]=(h16)b1.z; hb[7]=(h16)b1.w;
        *(half8*)&xbA[erow * XBP + ecol * 8] = ha;
        *(half8*)&xbB[erow * XBP + ecol * 8] = hb;
        const float* xa1 = p.x + ((size_t)1 * BB + r0A + erow) * II + ecol * 8;
        const float* xb1 = p.x + ((size_t)1 * BB + r0B + erow) * II + ecol * 8;
        paA = ((const float4*)xa1)[0]; pbA = ((const float4*)xa1)[1];
        paB = ((const float4*)xb1)[0]; pbB = ((const float4*)xb1)[1];
    }

    uint64_t gvA[8], gvB[8];
    const bool gatherer = (ecol != c);

    __syncthreads();

    for (int n = 1; n <= NSTEP; ++n) {
        const bool enc = (n <= TT);
        const int  parP = (n - 1) & 1;   // parity of s_{n-1}
        const int  parN = n & 1;         // parity of s_n

        // ---- [1] issue gB (s_B(n-1); published ~1 full B-phase ago) ----
        const uint64_t* gpB = slotB[parP] + (size_t)erow * XROW + ecol * 8;
        if (n > 1 && gatherer) ld8_issue(gpB, gvB);

        // ---- [2] wait gA (issued end of prev iter; vmcnt(8): gB stays
        //          in flight) + retry; fill sA remote ----
        if (n > 1 && gatherer) {
            const uint64_t* gpA = slotA[parP] + (size_t)erow * XROW + ecol * 8;
            WAIT_TIE8_VM8(gvA);
            retry8(gpA, gvA, (uint32_t)(n - 1));
            uint4 q0 = make_uint4((uint32_t)gvA[0], (uint32_t)gvA[1],
                                  (uint32_t)gvA[2], (uint32_t)gvA[3]);
            uint4 q1 = make_uint4((uint32_t)gvA[4], (uint32_t)gvA[5],
                                  (uint32_t)gvA[6], (uint32_t)gvA[7]);
            *(uint4*)&sA[erow * SBP + ecol * 16]     = q0;
            *(uint4*)&sA[erow * SBP + ecol * 16 + 8] = q1;
        }
        __syncthreads();   // (i) sA complete for step n

        // ---- [4] MFMA A ----
        f32x4 accA = {0.f, 0.f, 0.f, 0.f};
#pragma unroll
        for (int kc = 0; kc < 8; ++kc) {
            half8 a = *(const half8*)&sA[lrow * SBP + kc * 32 + lk8];
            accA = __builtin_amdgcn_mfma_f32_16x16x32_f16(a, bU[kc], accA, 0, 0, 0);
        }
        if (enc) {
#pragma unroll
            for (int kc = 0; kc < 4; ++kc) {
                half8 a = *(const half8*)&xbA[lrow * XBP + kc * 32 + lk8];
                accA = __builtin_amdgcn_mfma_f32_16x16x32_f16(a, bW[kc], accA, 0, 0, 0);
            }
        }
#pragma unroll
        for (int q = 0; q < 4; ++q)
            zbA[wave][(lane >> 4) * 4 + q][lrow] = accA[q];
        __syncthreads();   // (ii) zbA ready; sA/xbA reads done

        // ---- [5] gates A; own slice; publish A ----
        {
            float zi = zbA[0][erow][ecol] + biasLds[0][ecol];
            float zf = zbA[1][erow][ecol] + biasLds[1][ecol];
            float zo = zbA[2][erow][ecol] + biasLds[2][ecol];
            float zg = zbA[3][erow][ecol] + biasLds[3][ecol];
            float ig = sigmoidf_(zi), fg = sigmoidf_(zf);
            float og = sigmoidf_(zo), gg = tanhf_(zg);
            cstA = cstA * fg + gg * ig;
            float sv = tanhf_(cstA) * og;
            h16 svh = (h16)sv;
            sA[erow * SBP + c * 16 + ecol] = svh;
            if (!enc) {
                const int d = n - TT - 1;
                p.out[((size_t)d * BB + r0A + erow) * SS + c0 + ecol] = og;
            }
            if (n < NSTEP) {
                float so = __shfl_xor(sv, 1);
                if ((tid & 1) == 0) {
                    uint16_t lo = __builtin_bit_cast(uint16_t, svh);
                    uint16_t hi = __builtin_bit_cast(uint16_t, (h16)so);
                    uint64_t pk = ((uint64_t)(uint32_t)n << 32)
                                | (uint64_t)((uint32_t)lo | ((uint32_t)hi << 16));
                    st_ag64(slotA[parN] + (size_t)erow * XROW + c * 8 + (ecol >> 1), pk);
                }
            }
        }

        // ---- [6] wait gB (+retry); fill sB remote ----
        if (n > 1 && gatherer) {
            WAIT_TIE8_VM0(gvB);
            retry8(gpB, gvB, (uint32_t)(n - 1));
            uint4 q0 = make_uint4((uint32_t)gvB[0], (uint32_t)gvB[1],
                                  (uint32_t)gvB[2], (uint32_t)gvB[3]);
            uint4 q1 = make_uint4((uint32_t)gvB[4], (uint32_t)gvB[5],
                                  (uint32_t)gvB[6], (uint32_t)gvB[7]);
            *(uint4*)&sB[erow * SBP + ecol * 16]     = q0;
            *(uint4*)&sB[erow * SBP + ecol * 16 + 8] = q1;
        }
        __syncthreads();   // (iii) sB complete for step n

        // ---- [8] MFMA B ----
        f32x4 accB = {0.f, 0.f, 0.f, 0.f};
#pragma unroll
        for (int kc = 0; kc < 8; ++kc) {
            half8 a = *(const half8*)&sB[lrow * SBP + kc * 32 + lk8];
            accB = __builtin_amdgcn_mfma_f32_16x16x32_f16(a, bU[kc], accB, 0, 0, 0);
        }
        if (enc) {
#pragma unroll
            for (int kc = 0; kc < 4; ++kc) {
                half8 a = *(const half8*)&xbB[lrow * XBP + kc * 32 + lk8];
                accB = __builtin_amdgcn_mfma_f32_16x16x32_f16(a, bW[kc], accB, 0, 0, 0);
            }
        }
#pragma unroll
        for (int q = 0; q < 4; ++q)
            zbB[wave][(lane >> 4) * 4 + q][lrow] = accB[q];
        __syncthreads();   // (iv) zbB ready; sB/xbB reads done

        // ---- [9] gates B; own; publish B; stage x; issue gA' LAST ----
        {
            float zi = zbB[0][erow][ecol] + biasLds[0][ecol];
            float zf = zbB[1][erow][ecol] + biasLds[1][ecol];
            float zo = zbB[2][erow][ecol] + biasLds[2][ecol];
            float zg = zbB[3][erow][ecol] + biasLds[3][ecol];
            float ig = sigmoidf_(zi), fg = sigmoidf_(zf);
            float og = sigmoidf_(zo), gg = tanhf_(zg);
            cstB = cstB * fg + gg * ig;
            float sv = tanhf_(cstB) * og;
            h16 svh = (h16)sv;
            sB[erow * SBP + c * 16 + ecol] = svh;
            if (!enc) {
                const int d = n - TT - 1;
                p.out[((size_t)d * BB + r0B + erow) * SS + c0 + ecol] = og;
            }
            if (n < NSTEP) {
                float so = __shfl_xor(sv, 1);
                if ((tid & 1) == 0) {
                    uint16_t lo = __builtin_bit_cast(uint16_t, svh);
                    uint16_t hi = __builtin_bit_cast(uint16_t, (h16)so);
                    uint64_t pk = ((uint64_t)(uint32_t)n << 32)
                                | (uint64_t)((uint32_t)lo | ((uint32_t)hi << 16));
                    st_ag64(slotB[parN] + (size_t)erow * XROW + c * 8 + (ecol >> 1), pk);
                }
            }
        }
        // stage x_n for step n+1; prefetch x_{n+1} (older than gA' in vmcnt)
        if (n < TT) {
            half8 ha, hb;
            ha[0]=(h16)paA.x; ha[1]=(h16)paA.y; ha[2]=(h16)paA.z; ha[3]=(h16)paA.w;
            ha[4]=(h16)pbA.x; ha[5]=(h16)pbA.y; ha[6]=(h16)pbA.z; ha[7]=(h16)pbA.w;
            hb[0]=(h16)paB.x; hb[1]=(h16)paB.y; hb[2]=(h16)paB.z; hb[3]=(h16)paB.w;
            hb[4]=(h16)pbB.x; hb[5]=(h16)pbB.y; hb[6]=(h16)pbB.z; hb[7]=(h16)pbB.w;
            *(half8*)&xbA[erow * XBP + ecol * 8] = ha;
            *(half8*)&xbB[erow * XBP + ecol * 8] = hb;
            if (n + 1 < TT) {
                const float* xa = p.x + ((size_t)(n + 1) * BB + r0A + erow) * II + ecol * 8;
                const float* xb = p.x + ((size_t)(n + 1) * BB + r0B + erow) * II + ecol * 8;
                paA = ((const float4*)xa)[0]; pbA = ((const float4*)xa)[1];
                paB = ((const float4*)xb)[0]; pbB = ((const float4*)xb)[1];
            }
        }
        // issue gA' for s_A(n): peers' pubA was ~2 phases ago -> committed.
        // Issued LAST so next iteration's vmcnt(8) counts are exact.
        if (n < NSTEP && gatherer) {
            const uint64_t* gpA2 = slotA[parN] + (size_t)erow * XROW + ecol * 8;
            ld8_issue(gpA2, gvA);
        }
        // no barrier needed here: next write to sA (step [2]) is separated
        // from this iteration's sA reads by barriers (ii)..(i'); zbB reads
        // are separated from the next zbB write by (i'),(ii'),(iii').
    }
}

extern "C" void kernel_launch(void* const* d_in, const int* in_sizes, int n_in,
                              void* d_out, int out_size, void* d_ws, size_t ws_size,
                              hipStream_t stream) {
    Ptrs p;
    p.x  = (const float*)d_in[0];
    p.Wi = (const float*)d_in[1];  p.Ui = (const float*)d_in[2];  p.Bi = (const float*)d_in[3];
    p.Wf = (const float*)d_in[4];  p.Uf = (const float*)d_in[5];  p.Bf = (const float*)d_in[6];
    p.Wo = (const float*)d_in[7];  p.Uo = (const float*)d_in[8];  p.Bo = (const float*)d_in[9];
    p.Wg = (const float*)d_in[10]; p.Ug = (const float*)d_in[11]; p.Bg = (const float*)d_in[12];
    p.out = (float*)d_out;
    p.ws  = (uint32_t*)d_ws;

    // zero tags each launch: s_0 (tag 0, zero data) valid; replay-safe
    hipMemsetAsync(d_ws, 0, (size_t)2 * XPAR * sizeof(uint64_t), stream);

    // 128 blocks on 256 CUs: co-resident under plain launch; coop preferred
    // with fallback (r6 lesson: never trust a single launch path).
    void* args[] = {&p};
    hipError_t e = hipLaunchCooperativeKernel(lstm2, dim3(NBLK), dim3(256),
                                              args, 0, stream);
    if (e != hipSuccess) {
        hipLaunchKernelGGL(lstm2, dim3(NBLK), dim3(256), 0, stream, p);
    }
}

// Round 14
// 1767.991 us; speedup vs baseline: 3.9458x; 1.1330x over previous
//
#include <hip/hip_runtime.h>
#include <stdint.h>

// Problem constants
#define TT 256      // timesteps per phase
#define BB 256      // batch
#define II 128      // input dim
#define SS 256      // state dim
#define NSTEP (2*TT)
#define NBLK 256

typedef _Float16 h16;
typedef _Float16 half8 __attribute__((ext_vector_type(8)));
typedef float f32x4 __attribute__((ext_vector_type(4)));
typedef unsigned int u32x4 __attribute__((ext_vector_type(4)));

#define SBP 264     // s_buf padded row stride (halves)
#define XBP 136     // xbuf padded row stride (halves)

// Exchange: [parity][team][row 0..15][col_pair 0..127] of u64
//   u64 = { hi: step tag, lo: 2 x fp16 (even col in low half) }
// Tag-in-data (r7/r9/r10/r11-proven). Aligned 8B = single-copy atomic.
// Lap safety: producer writes s_{n+2} into a slot only after gathering all
// of s_{n+1}, which requires every team member to have finished reading s_n.
// Encode->decode handoff rides the kernel boundary (full ordering).
#define XROW 128
#define XTEAM (16 * XROW)        // 2048 u64 per team
#define XPAR  (16 * XTEAM)       // 32768 u64 per parity
#define CWS_OFF ((size_t)2 * XPAR)   // u64 offset of c-state dump (256x256 f32)

__device__ __forceinline__ float sigmoidf_(float z) {
    return __builtin_amdgcn_rcpf(1.0f + __expf(-z));
}
__device__ __forceinline__ float tanhf_(float z) {
    return 1.0f - 2.0f * __builtin_amdgcn_rcpf(1.0f + __expf(2.0f * z));
}

__device__ __forceinline__ uint64_t ld_ag64(const uint64_t* p) {
    return __hip_atomic_load(p, __ATOMIC_RELAXED, __HIP_MEMORY_SCOPE_AGENT);
}
__device__ __forceinline__ void st_ag64(uint64_t* p, uint64_t v) {
    __hip_atomic_store(p, v, __ATOMIC_RELAXED, __HIP_MEMORY_SCOPE_AGENT);
}

// ---- batched 8x8B device-coherent load, one wait (r9-proven) ----
__device__ __forceinline__ void ld8u64_sc1(const uint64_t* p, uint64_t* v) {
    asm volatile(
        "global_load_dwordx2 %0, %8, off sc1\n\t"
        "global_load_dwordx2 %1, %8, off offset:8 sc1\n\t"
        "global_load_dwordx2 %2, %8, off offset:16 sc1\n\t"
        "global_load_dwordx2 %3, %8, off offset:24 sc1\n\t"
        "global_load_dwordx2 %4, %8, off offset:32 sc1\n\t"
        "global_load_dwordx2 %5, %8, off offset:40 sc1\n\t"
        "global_load_dwordx2 %6, %8, off offset:48 sc1\n\t"
        "global_load_dwordx2 %7, %8, off offset:56 sc1\n\t"
        "s_waitcnt vmcnt(0)"
        : "=&v"(v[0]), "=&v"(v[1]), "=&v"(v[2]), "=&v"(v[3]),
          "=&v"(v[4]), "=&v"(v[5]), "=&v"(v[6]), "=&v"(v[7])
        : "v"(p) : "memory");
}

// ---- batched 16x8B loads at offsets kc*128 + j*8 (r10/r11-proven) ----
#define LD16_BODY(SUFFIX)                                                   \
    asm volatile(                                                           \
        "global_load_dwordx2 %0,  %16, off sc1\n\t"                         \
        "global_load_dwordx2 %1,  %16, off offset:8 sc1\n\t"                \
        "global_load_dwordx2 %2,  %16, off offset:16 sc1\n\t"               \
        "global_load_dwordx2 %3,  %16, off offset:24 sc1\n\t"               \
        "global_load_dwordx2 %4,  %16, off offset:128 sc1\n\t"              \
        "global_load_dwordx2 %5,  %16, off offset:136 sc1\n\t"              \
        "global_load_dwordx2 %6,  %16, off offset:144 sc1\n\t"              \
        "global_load_dwordx2 %7,  %16, off offset:152 sc1\n\t"              \
        "global_load_dwordx2 %8,  %16, off offset:256 sc1\n\t"              \
        "global_load_dwordx2 %9,  %16, off offset:264 sc1\n\t"              \
        "global_load_dwordx2 %10, %16, off offset:272 sc1\n\t"              \
        "global_load_dwordx2 %11, %16, off offset:280 sc1\n\t"              \
        "global_load_dwordx2 %12, %16, off offset:384 sc1\n\t"              \
        "global_load_dwordx2 %13, %16, off offset:392 sc1\n\t"              \
        "global_load_dwordx2 %14, %16, off offset:400 sc1\n\t"              \
        "global_load_dwordx2 %15, %16, off offset:408 sc1" SUFFIX           \
        : "=&v"(v[0]), "=&v"(v[1]), "=&v"(v[2]), "=&v"(v[3]),               \
          "=&v"(v[4]), "=&v"(v[5]), "=&v"(v[6]), "=&v"(v[7]),               \
          "=&v"(v[8]), "=&v"(v[9]), "=&v"(v[10]), "=&v"(v[11]),             \
          "=&v"(v[12]), "=&v"(v[13]), "=&v"(v[14]), "=&v"(v[15])            \
        : "v"(p) : "memory")

__device__ __forceinline__ void ld16_sc1_nowait(const uint64_t* p, uint64_t* v) {
    LD16_BODY("");
}
__device__ __forceinline__ void ld16_sc1_wait(const uint64_t* p, uint64_t* v) {
    LD16_BODY("\n\ts_waitcnt vmcnt(0)");
}

struct Ptrs {
    const float *x;
    const float *Wi, *Ui, *Bi, *Wf, *Uf, *Bf, *Wo, *Uo, *Bo, *Wg, *Ug, *Bg;
    float* out;
    uint32_t* ws;
};

// ======================= ENCODE: r9 structure, steps 1..256 =================
__global__ __launch_bounds__(256, 1) void lstm_enc(Ptrs p) {
    const int bid  = blockIdx.x;
    const int tid  = threadIdx.x;
    const int wave = tid >> 6;            // gate: 0=i 1=f 2=o 3=g
    const int lane = tid & 63;
    const int lrow = lane & 15;
    const int lk8  = (lane >> 4) * 8;
    const int erow = tid >> 4;
    const int ecol = tid & 15;

    const int team = bid >> 4;
    const int c    = bid & 15;
    const int r0   = team * 16;
    const int c0   = c * 16;

    __shared__ __align__(16) h16 s_buf[16 * SBP];
    __shared__ __align__(16) h16 xbuf[16 * XBP];
    __shared__ float zbuf[4][16][17];
    __shared__ float biasLds[4][16];

    uint64_t* xch   = (uint64_t*)p.ws;
    uint64_t* slot0 = xch + (size_t)team * XTEAM;
    uint64_t* slot1 = xch + XPAR + (size_t)team * XTEAM;
    float*    cws   = (float*)(xch + CWS_OFF);

    const float* Uptr[4] = {p.Ui, p.Uf, p.Uo, p.Ug};
    const float* Wptr[4] = {p.Wi, p.Wf, p.Wo, p.Wg};
    const float* Bptr[4] = {p.Bi, p.Bf, p.Bo, p.Bg};

    if (tid < 64) biasLds[tid >> 4][tid & 15] = Bptr[tid >> 4][c0 + (tid & 15)];
    for (int idx = tid; idx < 16 * SBP; idx += 256) s_buf[idx] = (h16)0.0f;

    // B (16x16x32): lane holds B[k=(lane>>4)*8+q][col=lane&15] (r9-proven)
    const float* Ug = Uptr[wave];
    const float* Wg = Wptr[wave];
    half8 bU[8];
#pragma unroll
    for (int kc = 0; kc < 8; ++kc)
#pragma unroll
        for (int q = 0; q < 8; ++q)
            bU[kc][q] = (h16)Ug[(size_t)(kc * 32 + lk8 + q) * SS + c0 + lrow];
    half8 bW[4];
#pragma unroll
    for (int kc = 0; kc < 4; ++kc)
#pragma unroll
        for (int q = 0; q < 8; ++q)
            bW[kc][q] = (h16)Wg[(size_t)(kc * 32 + lk8 + q) * SS + c0 + lrow];

    float cst = 0.0f;

    float4 pa, pb;
    {
        const float* xp = p.x + ((size_t)0 * BB + r0 + erow) * II + ecol * 8;
        pa = ((const float4*)xp)[0];
        pb = ((const float4*)xp)[1];
        half8 h;
        h[0]=(h16)pa.x; h[1]=(h16)pa.y; h[2]=(h16)pa.z; h[3]=(h16)pa.w;
        h[4]=(h16)pb.x; h[5]=(h16)pb.y; h[6]=(h16)pb.z; h[7]=(h16)pb.w;
        *(half8*)&xbuf[erow * XBP + ecol * 8] = h;
        const float* xp1 = p.x + ((size_t)1 * BB + r0 + erow) * II + ecol * 8;
        pa = ((const float4*)xp1)[0];
        pb = ((const float4*)xp1)[1];
    }
    __syncthreads();

    for (int n = 1; n <= TT; ++n) {
        // ---- MFMA: z[16x16] for gate `wave` ----
        f32x4 acc = {0.f, 0.f, 0.f, 0.f};
#pragma unroll
        for (int kc = 0; kc < 8; ++kc) {
            half8 a = *(const half8*)&s_buf[lrow * SBP + kc * 32 + lk8];
            acc = __builtin_amdgcn_mfma_f32_16x16x32_f16(a, bU[kc], acc, 0, 0, 0);
        }
#pragma unroll
        for (int kc = 0; kc < 4; ++kc) {
            half8 a = *(const half8*)&xbuf[lrow * XBP + kc * 32 + lk8];
            acc = __builtin_amdgcn_mfma_f32_16x16x32_f16(a, bW[kc], acc, 0, 0, 0);
        }
#pragma unroll
        for (int q = 0; q < 4; ++q)
            zbuf[wave][(lane >> 4) * 4 + q][lrow] = acc[q];
        __syncthreads();   // barrier A: zbuf ready; s_buf/xbuf reads done

        // ---- gates / state update ----
        float zi = zbuf[0][erow][ecol] + biasLds[0][ecol];
        float zf = zbuf[1][erow][ecol] + biasLds[1][ecol];
        float zo = zbuf[2][erow][ecol] + biasLds[2][ecol];
        float zg = zbuf[3][erow][ecol] + biasLds[3][ecol];
        float ig = sigmoidf_(zi), fg = sigmoidf_(zf);
        float og = sigmoidf_(zo), gg = tanhf_(zg);
        cst = cst * fg + gg * ig;
        float sv = tanhf_(cst) * og;

        h16 svh = (h16)sv;
        s_buf[erow * SBP + c * 16 + ecol] = svh;   // own slice direct

        uint64_t* slotP = (n & 1) ? slot1 : slot0;
        // ---- publish s_n (incl. n=256 for decode handoff) ----
        {
            float so = __shfl_xor(sv, 1);
            if ((tid & 1) == 0) {
                uint16_t lo = __builtin_bit_cast(uint16_t, svh);
                uint16_t hi = __builtin_bit_cast(uint16_t, (h16)so);
                uint64_t pk = ((uint64_t)(uint32_t)n << 32)
                            | (uint64_t)((uint32_t)lo | ((uint32_t)hi << 16));
                st_ag64(slotP + (size_t)erow * XROW + c * 8 + (ecol >> 1), pk);
            }
        }

        if (n < TT) {
            // ---- stage x_n NOW (covers the gather RT; xbuf reads finished
            //      at barrier A); issue x_{n+1} prefetch ----
            {
                half8 h;
                h[0]=(h16)pa.x; h[1]=(h16)pa.y; h[2]=(h16)pa.z; h[3]=(h16)pa.w;
                h[4]=(h16)pb.x; h[5]=(h16)pb.y; h[6]=(h16)pb.z; h[7]=(h16)pb.w;
                *(half8*)&xbuf[erow * XBP + ecol * 8] = h;
                if (n + 1 < TT) {
                    const float* xp = p.x + ((size_t)(n + 1) * BB + r0 + erow) * II + ecol * 8;
                    pa = ((const float4*)xp)[0];
                    pb = ((const float4*)xp)[1];
                }
            }
            // ---- gather s_n (batched passes, r9-proven) ----
            if (ecol != c) {
                const uint64_t* gp = slotP + (size_t)erow * XROW + ecol * 8;
                const uint32_t want = (uint32_t)n;
                uint64_t gv[8];
                ld8u64_sc1(gp, gv);
                for (;;) {
                    bool fresh = true;
#pragma unroll
                    for (int j = 0; j < 8; ++j)
                        fresh = fresh && ((uint32_t)(gv[j] >> 32) == want);
                    if (__builtin_expect(fresh, 1)) break;
                    ld8u64_sc1(gp, gv);
                }
                uint4 q0 = make_uint4((uint32_t)gv[0], (uint32_t)gv[1],
                                      (uint32_t)gv[2], (uint32_t)gv[3]);
                uint4 q1 = make_uint4((uint32_t)gv[4], (uint32_t)gv[5],
                                      (uint32_t)gv[6], (uint32_t)gv[7]);
                *(uint4*)&s_buf[erow * SBP + ecol * 16]     = q0;
                *(uint4*)&s_buf[erow * SBP + ecol * 16 + 8] = q1;
            }
            __syncthreads();   // barrier B: s_buf/xbuf complete for step n+1
        }
    }

    // ---- dump c_256 for decode (plain store; kernel boundary orders it) ----
    cws[(size_t)(r0 + erow) * SS + c0 + ecol] = cst;
}

// ====== DECODE: barrier-free single-wave roles, steps 257..512 ==============
__global__ __launch_bounds__(64, 1) void lstm_dec(Ptrs p) {
    const int lane = threadIdx.x;
    const int role = blockIdx.x;           // 0..255
    const int team = role >> 4;
    const int cb   = role & 15;
    const int r0   = team * 16;
    const int c0   = cb * 16;
    const int lrow = lane & 15;
    const int lgrp = lane >> 4;
    const int lk8  = lgrp * 8;

    // 96 KB pad -> 1 block/CU (r11-proven); pinned vs DCE.
    __shared__ __align__(16) uint32_t spread_pad[24576];
    spread_pad[lane] = (uint32_t)lane;
    asm volatile("" :: "v"(&spread_pad[lane]) : "memory");

    uint64_t* xch   = (uint64_t*)p.ws;
    uint64_t* slot0 = xch + (size_t)team * XTEAM;
    uint64_t* slot1 = xch + XPAR + (size_t)team * XTEAM;
    const float* cws = (const float*)(xch + CWS_OFF);

    const float* Uptr[4] = {p.Ui, p.Uf, p.Uo, p.Ug};
    const float* Bptr[4] = {p.Bi, p.Bf, p.Bo, p.Bg};

    // all 4 gates' U fragments; NO bW, NO xv -> ~235 regs, no spill
    half8 bU[4][8];
#pragma unroll
    for (int g = 0; g < 4; ++g) {
        const float* Ug = Uptr[g];
#pragma unroll
        for (int kc = 0; kc < 8; ++kc)
#pragma unroll
            for (int q = 0; q < 8; ++q)
                bU[g][kc][q] = (h16)Ug[(size_t)(kc * 32 + lk8 + q) * SS + c0 + lrow];
    }
    float bias[4];
#pragma unroll
    for (int g = 0; g < 4; ++g) bias[g] = Bptr[g][c0 + lrow];

    // c_256 from encode dump (kernel boundary = full coherence)
    float cst[4];
#pragma unroll
    for (int q = 0; q < 4; ++q)
        cst[q] = cws[(size_t)(r0 + lgrp * 4 + q) * SS + c0 + lrow];

    for (int n = TT + 1; n <= NSTEP; ++n) {
        // ---- spin-gather s_{n-1}: 32 loads in flight, one wait/pass ----
        const uint32_t want = (uint32_t)(n - 1);
        const uint64_t* gb = (((n - 1) & 1) ? slot1 : slot0)
                           + (size_t)lrow * XROW + lgrp * 4;
        uint64_t gv[32];
        ld16_sc1_nowait(gb, gv);
        ld16_sc1_wait(gb + 64, gv + 16);
        for (;;) {
            bool ok = true;
#pragma unroll
            for (int i = 0; i < 32; ++i)
                ok = ok && ((uint32_t)(gv[i] >> 32) == want);
            if (__builtin_expect(ok, 1)) break;
            ld16_sc1_nowait(gb, gv);
            ld16_sc1_wait(gb + 64, gv + 16);
        }

        // ---- s @ U: 32 MFMAs, 4 independent gate chains ----
        f32x4 acc[4];
#pragma unroll
        for (int g = 0; g < 4; ++g) acc[g] = (f32x4){0.f, 0.f, 0.f, 0.f};
#pragma unroll
        for (int kc = 0; kc < 8; ++kc) {
            u32x4 t;
            t.x = (uint32_t)gv[kc*4+0]; t.y = (uint32_t)gv[kc*4+1];
            t.z = (uint32_t)gv[kc*4+2]; t.w = (uint32_t)gv[kc*4+3];
            half8 a = __builtin_bit_cast(half8, t);
#pragma unroll
            for (int g = 0; g < 4; ++g)
                acc[g] = __builtin_amdgcn_mfma_f32_16x16x32_f16(a, bU[g][kc], acc[g], 0, 0, 0);
        }

        // ---- gates + state update, in-register (C/D: col=lane&15,
        //      row=(lane>>4)*4+q) ----
        float sv[4], ov[4];
#pragma unroll
        for (int q = 0; q < 4; ++q) {
            float zi = acc[0][q] + bias[0];
            float zf = acc[1][q] + bias[1];
            float zo = acc[2][q] + bias[2];
            float zg = acc[3][q] + bias[3];
            float ig = sigmoidf_(zi), fg = sigmoidf_(zf);
            float og = sigmoidf_(zo), gg = tanhf_(zg);
            cst[q] = cst[q] * fg + gg * ig;
            sv[q] = tanhf_(cst[q]) * og;
            ov[q] = og;
        }

        // ---- publish s_n first (team critical path) ----
        if (n < NSTEP) {
            uint64_t* pb = ((n & 1) ? slot1 : slot0);
            const uint64_t tag = (uint64_t)(uint32_t)n << 32;
#pragma unroll
            for (int q = 0; q < 4; ++q) {
                float so = __shfl_xor(sv[q], 1);
                if ((lane & 1) == 0) {
                    uint16_t lo = __builtin_bit_cast(uint16_t, (h16)sv[q]);
                    uint16_t hi = __builtin_bit_cast(uint16_t, (h16)so);
                    uint64_t pk = tag | (uint64_t)((uint32_t)lo | ((uint32_t)hi << 16));
                    st_ag64(pb + (size_t)(lgrp * 4 + q) * XROW + (c0 >> 1) + (lrow >> 1), pk);
                }
            }
        }

        // ---- output store (off critical path) ----
        const int d = n - TT - 1;
#pragma unroll
        for (int q = 0; q < 4; ++q)
            p.out[((size_t)d * BB + r0 + lgrp * 4 + q) * SS + c0 + lrow] = ov[q];
    }
}

extern "C" void kernel_launch(void* const* d_in, const int* in_sizes, int n_in,
                              void* d_out, int out_size, void* d_ws, size_t ws_size,
                              hipStream_t stream) {
    Ptrs p;
    p.x  = (const float*)d_in[0];
    p.Wi = (const float*)d_in[1];  p.Ui = (const float*)d_in[2];  p.Bi = (const float*)d_in[3];
    p.Wf = (const float*)d_in[4];  p.Uf = (const float*)d_in[5];  p.Bf = (const float*)d_in[6];
    p.Wo = (const float*)d_in[7];  p.Uo = (const float*)d_in[8];  p.Bo = (const float*)d_in[9];
    p.Wg = (const float*)d_in[10]; p.Ug = (const float*)d_in[11]; p.Bg = (const float*)d_in[12];
    p.out = (float*)d_out;
    p.ws  = (uint32_t*)d_ws;

    // zero tags each launch (replay-safe); c-dump region fully rewritten by
    // encode before decode reads it, so no memset needed there.
    hipMemsetAsync(d_ws, 0, (size_t)2 * XPAR * sizeof(uint64_t), stream);

    void* args[] = {&p};
    hipError_t e = hipLaunchCooperativeKernel(lstm_enc, dim3(NBLK), dim3(256),
                                              args, 0, stream);
    if (e != hipSuccess) {
        hipLaunchKernelGGL(lstm_enc, dim3(NBLK), dim3(256), 0, stream, p);
    }
    e = hipLaunchCooperativeKernel(lstm_dec, dim3(NBLK), dim3(64),
                                   args, 0, stream);
    if (e != hipSuccess) {
        hipLaunchKernelGGL(lstm_dec, dim3(NBLK), dim3(64), 0, stream, p);
    }
}

// Round 15
// 1606.052 us; speedup vs baseline: 4.3437x; 1.1008x over previous
//
#include <hip/hip_runtime.h>
#include <stdint.h>

// Problem constants
#define TT 256      // timesteps per phase
#define BB 256      // batch
#define II 128      // input dim
#define SS 256      // state dim
#define NSTEP (2*TT)
#define NBLK 256    // 16 teams x 16 col-blocks; r9-proven 256x256 shape

typedef _Float16 h16;
typedef _Float16 half8 __attribute__((ext_vector_type(8)));
typedef float f32x4 __attribute__((ext_vector_type(4)));

#define SBP 264     // s_buf padded row stride (halves)
#define XBP 136     // xbuf padded row stride (halves)

// Exchange: [parity][team][row 0..15][col_pair 0..127] of u64
//   u64 = { hi: step tag, lo: 2 x fp16 (even col in low half) }
// Tag-in-data (r7/r9/r13/r14-proven): no flags, no drains. Aligned 8B
// accesses are single-copy atomic. Lap safety: producer writes s_{n+2} into
// a slot only after gathering ALL of s_{n+1}, which requires every team
// member to have finished reading s_n from that slot.
#define XROW 128
#define XTEAM (16 * XROW)        // 2048 u64 per team
#define XPAR  (16 * XTEAM)       // 32768 u64 per parity

__device__ __forceinline__ float sigmoidf_(float z) {
    return __builtin_amdgcn_rcpf(1.0f + __expf(-z));
}
__device__ __forceinline__ float tanhf_(float z) {
    return 1.0f - 2.0f * __builtin_amdgcn_rcpf(1.0f + __expf(2.0f * z));
}

__device__ __forceinline__ void st_ag64(uint64_t* p, uint64_t v) {
    __hip_atomic_store(p, v, __ATOMIC_RELAXED, __HIP_MEMORY_SCOPE_AGENT);
}

// 8 independent 8B device-coherent loads (sc1 = device scope).
#define LD8_OPS                                                             \
        "global_load_dwordx2 %0, %8, off sc1\n\t"                           \
        "global_load_dwordx2 %1, %8, off offset:8 sc1\n\t"                  \
        "global_load_dwordx2 %2, %8, off offset:16 sc1\n\t"                 \
        "global_load_dwordx2 %3, %8, off offset:24 sc1\n\t"                 \
        "global_load_dwordx2 %4, %8, off offset:32 sc1\n\t"                 \
        "global_load_dwordx2 %5, %8, off offset:40 sc1\n\t"                 \
        "global_load_dwordx2 %6, %8, off offset:48 sc1\n\t"                 \
        "global_load_dwordx2 %7, %8, off offset:56 sc1"
#define LD8_OUTS(v)                                                         \
        : "=&v"(v[0]), "=&v"(v[1]), "=&v"(v[2]), "=&v"(v[3]),               \
          "=&v"(v[4]), "=&v"(v[5]), "=&v"(v[6]), "=&v"(v[7])

// issue-only: loads go in flight, no wait (r13-proven)
__device__ __forceinline__ void ld8_issue(const uint64_t* p, uint64_t* v) {
    asm volatile(LD8_OPS LD8_OUTS(v) : "v"(p) : "memory");
}
// combined issue + wait (retry path; r9-proven)
__device__ __forceinline__ void ld8_wait(const uint64_t* p, uint64_t* v) {
    asm volatile(LD8_OPS "\n\ts_waitcnt vmcnt(0)" LD8_OUTS(v) : "v"(p) : "memory");
}
// wait with gather regs TIED so no consumer is hoisted above it (rule 18);
// r13-proven pattern.
#define WAIT_TIE8_VM0(v)                                                    \
    asm volatile("s_waitcnt vmcnt(0)"                                       \
        : "+v"(v[0]), "+v"(v[1]), "+v"(v[2]), "+v"(v[3]),                   \
          "+v"(v[4]), "+v"(v[5]), "+v"(v[6]), "+v"(v[7]) :: "memory");      \
    __builtin_amdgcn_sched_barrier(0)

struct Ptrs {
    const float *x;
    const float *Wi, *Ui, *Bi, *Wf, *Uf, *Bf, *Wo, *Uo, *Bo, *Wg, *Ug, *Bg;
    float* out;
    uint32_t* ws;
};

__global__ __launch_bounds__(256, 1) void lstm_persist(Ptrs p) {
    const int bid  = blockIdx.x;
    const int tid  = threadIdx.x;
    const int wave = tid >> 6;            // gate: 0=i 1=f 2=o 3=g
    const int lane = tid & 63;
    const int lrow = lane & 15;           // A-row / B-col within tile
    const int lk8  = (lane >> 4) * 8;     // k sub-offset within 32-chunk
    const int erow = tid >> 4;            // elementwise (row,col) ownership
    const int ecol = tid & 15;

    const int team = bid >> 4;            // batch rows [team*16, +16)
    const int c    = bid & 15;            // col block  [c*16, +16)
    const int r0   = team * 16;
    const int c0   = c * 16;

    __shared__ __align__(16) h16 s_buf[16 * SBP];
    __shared__ __align__(16) h16 xbuf[16 * XBP];
    __shared__ float zbuf[4][16][17];
    __shared__ float biasLds[4][16];

    uint64_t* xch   = (uint64_t*)p.ws;
    uint64_t* slot0 = xch + (size_t)team * XTEAM;
    uint64_t* slot1 = xch + XPAR + (size_t)team * XTEAM;

    const float* Uptr[4] = {p.Ui, p.Uf, p.Uo, p.Ug};
    const float* Wptr[4] = {p.Wi, p.Wf, p.Wo, p.Wg};
    const float* Bptr[4] = {p.Bi, p.Bf, p.Bo, p.Bg};

    if (tid < 64) biasLds[tid >> 4][tid & 15] = Bptr[tid >> 4][c0 + (tid & 15)];
    for (int idx = tid; idx < 16 * SBP; idx += 256) s_buf[idx] = (h16)0.0f;

    // B (16x16x32): lane holds B[k=(lane>>4)*8+q][col=lane&15] (r9-proven)
    const float* Ug = Uptr[wave];
    const float* Wg = Wptr[wave];
    half8 bU[8];
#pragma unroll
    for (int kc = 0; kc < 8; ++kc)
#pragma unroll
        for (int q = 0; q < 8; ++q)
            bU[kc][q] = (h16)Ug[(size_t)(kc * 32 + lk8 + q) * SS + c0 + lrow];
    half8 bW[4];
#pragma unroll
    for (int kc = 0; kc < 4; ++kc)
#pragma unroll
        for (int q = 0; q < 8; ++q)
            bW[kc][q] = (h16)Wg[(size_t)(kc * 32 + lk8 + q) * SS + c0 + lrow];

    float cst = 0.0f;   // cell state owned by this thread: (erow, ecol)

    // ---- stage x tile for t=0; prefetch t=1 ----
    float4 pa, pb;
    {
        const float* xp = p.x + ((size_t)0 * BB + r0 + erow) * II + ecol * 8;
        pa = ((const float4*)xp)[0];
        pb = ((const float4*)xp)[1];
        half8 h;
        h[0]=(h16)pa.x; h[1]=(h16)pa.y; h[2]=(h16)pa.z; h[3]=(h16)pa.w;
        h[4]=(h16)pb.x; h[5]=(h16)pb.y; h[6]=(h16)pb.z; h[7]=(h16)pb.w;
        *(half8*)&xbuf[erow * XBP + ecol * 8] = h;
        const float* xp1 = p.x + ((size_t)1 * BB + r0 + erow) * II + ecol * 8;
        pa = ((const float4*)xp1)[0];
        pb = ((const float4*)xp1)[1];
    }
    __syncthreads();

    const bool gatherer = (ecol != c);

    for (int n = 1; n <= NSTEP; ++n) {
        const bool enc = (n <= TT);

        // ---- [1] MFMA: z[16x16] for gate `wave` ----
        f32x4 acc = {0.f, 0.f, 0.f, 0.f};
#pragma unroll
        for (int kc = 0; kc < 8; ++kc) {
            half8 a = *(const half8*)&s_buf[lrow * SBP + kc * 32 + lk8];
            acc = __builtin_amdgcn_mfma_f32_16x16x32_f16(a, bU[kc], acc, 0, 0, 0);
        }
        if (enc) {
#pragma unroll
            for (int kc = 0; kc < 4; ++kc) {
                half8 a = *(const half8*)&xbuf[lrow * XBP + kc * 32 + lk8];
                acc = __builtin_amdgcn_mfma_f32_16x16x32_f16(a, bW[kc], acc, 0, 0, 0);
            }
        }
        // C/D layout: col=lane&15, row=(lane>>4)*4+reg (m89-verified)
#pragma unroll
        for (int q = 0; q < 4; ++q)
            zbuf[wave][(lane >> 4) * 4 + q][lrow] = acc[q];
        __syncthreads();   // barrier A: zbuf ready; s_buf/xbuf reads done

        // ---- [2] gates / state update ----
        float zi = zbuf[0][erow][ecol] + biasLds[0][ecol];
        float zf = zbuf[1][erow][ecol] + biasLds[1][ecol];
        float zo = zbuf[2][erow][ecol] + biasLds[2][ecol];
        float zg = zbuf[3][erow][ecol] + biasLds[3][ecol];
        float ig = sigmoidf_(zi), fg = sigmoidf_(zf);
        float og = sigmoidf_(zo), gg = tanhf_(zg);
        cst = cst * fg + gg * ig;
        float sv = tanhf_(cst) * og;

        h16 svh = (h16)sv;
        s_buf[erow * SBP + c * 16 + ecol] = svh;   // own slice direct to LDS

        if (n < NSTEP) {
            uint64_t* slotP = (n & 1) ? slot1 : slot0;

            // ---- [3] publish s_n FIRST (team critical path) ----
            {
                float so = __shfl_xor(sv, 1);
                if ((tid & 1) == 0) {
                    uint16_t lo = __builtin_bit_cast(uint16_t, svh);
                    uint16_t hi = __builtin_bit_cast(uint16_t, (h16)so);
                    uint64_t pk = ((uint64_t)(uint32_t)n << 32)
                                | (uint64_t)((uint32_t)lo | ((uint32_t)hi << 16));
                    st_ag64(slotP + (size_t)erow * XROW + c * 8 + (ecol >> 1), pk);
                }
            }

            // ---- [4] issue first gather pass NOW (RT rides under [5]) ----
            const uint64_t* gp = slotP + (size_t)erow * XROW + ecol * 8;
            uint64_t gv[8];
            if (gatherer) ld8_issue(gp, gv);

            // ---- [5] off-path work: stage x (enc) / out store (dec) ----
            if (enc) {
                if (n < TT) {
                    half8 h;
                    h[0]=(h16)pa.x; h[1]=(h16)pa.y; h[2]=(h16)pa.z; h[3]=(h16)pa.w;
                    h[4]=(h16)pb.x; h[5]=(h16)pb.y; h[6]=(h16)pb.z; h[7]=(h16)pb.w;
                    *(half8*)&xbuf[erow * XBP + ecol * 8] = h;
                    if (n + 1 < TT) {
                        const float* xp = p.x + ((size_t)(n + 1) * BB + r0 + erow) * II + ecol * 8;
                        pa = ((const float4*)xp)[0];
                        pb = ((const float4*)xp)[1];
                    }
                }
            } else {
                const int d = n - TT - 1;
                p.out[((size_t)d * BB + r0 + erow) * SS + c0 + ecol] = og;
            }

            // ---- [6] wait + retry gather; fill s_buf remote ----
            if (gatherer) {
                WAIT_TIE8_VM0(gv);
                const uint32_t want = (uint32_t)n;
                for (;;) {
                    bool fresh = true;
#pragma unroll
                    for (int j = 0; j < 8; ++j)
                        fresh = fresh && ((uint32_t)(gv[j] >> 32) == want);
                    if (__builtin_expect(fresh, 1)) break;
                    ld8_wait(gp, gv);
                }
                uint4 q0 = make_uint4((uint32_t)gv[0], (uint32_t)gv[1],
                                      (uint32_t)gv[2], (uint32_t)gv[3]);
                uint4 q1 = make_uint4((uint32_t)gv[4], (uint32_t)gv[5],
                                      (uint32_t)gv[6], (uint32_t)gv[7]);
                *(uint4*)&s_buf[erow * SBP + ecol * 16]     = q0;
                *(uint4*)&s_buf[erow * SBP + ecol * 16 + 8] = q1;
            }
            __syncthreads();   // barrier B: s_buf/xbuf complete for step n+1
        } else {
            // final step: output only
            const int d = n - TT - 1;
            p.out[((size_t)d * BB + r0 + erow) * SS + c0 + ecol] = og;
        }
    }
}

extern "C" void kernel_launch(void* const* d_in, const int* in_sizes, int n_in,
                              void* d_out, int out_size, void* d_ws, size_t ws_size,
                              hipStream_t stream) {
    Ptrs p;
    p.x  = (const float*)d_in[0];
    p.Wi = (const float*)d_in[1];  p.Ui = (const float*)d_in[2];  p.Bi = (const float*)d_in[3];
    p.Wf = (const float*)d_in[4];  p.Uf = (const float*)d_in[5];  p.Bf = (const float*)d_in[6];
    p.Wo = (const float*)d_in[7];  p.Uo = (const float*)d_in[8];  p.Bo = (const float*)d_in[9];
    p.Wg = (const float*)d_in[10]; p.Ug = (const float*)d_in[11]; p.Bg = (const float*)d_in[12];
    p.out = (float*)d_out;
    p.ws  = (uint32_t*)d_ws;

    // zero tags each launch -> no stale-tag acceptance, replay-safe
    hipMemsetAsync(d_ws, 0, (size_t)2 * XPAR * sizeof(uint64_t), stream);

    // r9-proven coop shape; plain-launch fallback (protocol needs only
    // de-facto co-residency of 256 blocks on 256 CUs).
    void* args[] = {&p};
    hipError_t e = hipLaunchCooperativeKernel(lstm_persist, dim3(NBLK), dim3(256),
                                              args, 0, stream);
    if (e != hipSuccess) {
        hipLaunchKernelGGL(lstm_persist, dim3(NBLK), dim3(256), 0, stream, p);
    }
}